// Round 1
// baseline (857.421 us; speedup 1.0000x reference)
//
#include <hip/hip_runtime.h>
#include <hip/hip_bf16.h>

typedef __attribute__((ext_vector_type(8))) short short8;
typedef __attribute__((ext_vector_type(4))) float f32x4;

#define NN 16384
#define DD 128
#define NE 262144
#define NG 32
#define SS 512
#define NH 8
#define DHD 16
#define BN_EPS 1e-5f

__device__ __forceinline__ unsigned int pk2(float a, float b) {
    union { __hip_bfloat16 h; unsigned short u; } ca, cb;
    ca.h = __float2bfloat16(a);
    cb.h = __float2bfloat16(b);
    return (unsigned int)ca.u | ((unsigned int)cb.u << 16);
}

// ---------------- GINE scatter: agg[dst] += relu(x[src] + edge_attr) ----------------
__global__ __launch_bounds__(256) void gine_scatter(
    const float* __restrict__ x, const int* __restrict__ src, const int* __restrict__ dst,
    const float* __restrict__ ea, float* __restrict__ agg)
{
    long long t = (long long)blockIdx.x * 256 + threadIdx.x;
    int lane = (int)(t & 31);
    long long e = t >> 5;
    if (e >= NE) return;
    int s = src[e], d = dst[e];
    float4 xv = ((const float4*)(x + (size_t)s * DD))[lane];
    float4 ev = ((const float4*)(ea + (size_t)e * DD))[lane];
    float4 m;
    m.x = fmaxf(xv.x + ev.x, 0.f);
    m.y = fmaxf(xv.y + ev.y, 0.f);
    m.z = fmaxf(xv.z + ev.z, 0.f);
    m.w = fmaxf(xv.w + ev.w, 0.f);
    float* ap = agg + (size_t)d * DD + lane * 4;
    atomicAdd(ap + 0, m.x);
    atomicAdd(ap + 1, m.y);
    atomicAdd(ap + 2, m.z);
    atomicAdd(ap + 3, m.w);
}

// ---------------- bf16 MFMA GEMM, BT layout: out = epi(A(+A2) @ W^T + bias) (+res) --
// A: [M,K] f32 row-major, W: [Ncols,K] f32 row-major. BM=BN=128, BK=64, 4 waves (2x2).
template<bool RELU, bool ADD_A2, bool HAS_RES>
__global__ __launch_bounds__(256) void gemm_bt(
    const float* __restrict__ A, const float* __restrict__ A2,
    const float* __restrict__ W, const float* __restrict__ bias,
    const float* __restrict__ res, float* __restrict__ out,
    int K, int Ncols)
{
    constexpr int BK = 64;
    __shared__ unsigned short Ash[128 * BK];
    __shared__ unsigned short Wsh[128 * BK];
    const int tid  = threadIdx.x;
    const int lane = tid & 63;
    const int wid  = tid >> 6;
    const int wm   = wid >> 1, wn = wid & 1;
    const int brow = blockIdx.x * 128;
    const int bcol = blockIdx.y * 128;

    f32x4 acc[4][4] = {};

    for (int k0 = 0; k0 < K; k0 += BK) {
        // stage A and W tiles (f32 -> bf16, XOR-swizzled rows to kill bank conflicts)
        #pragma unroll
        for (int i = 0; i < 4; ++i) {
            int idx = tid + 256 * i;
            int row = idx >> 3;
            int kc  = (idx & 7) * 8;
            int off = row * (BK * 2) + ((kc * 2) ^ ((row & 7) << 4));
            {
                const float* sp = A + (size_t)(brow + row) * K + k0 + kc;
                float4 lo = *(const float4*)sp;
                float4 hi = *(const float4*)(sp + 4);
                if (ADD_A2) {
                    const float* s2 = A2 + (size_t)(brow + row) * K + k0 + kc;
                    float4 l2 = *(const float4*)s2;
                    float4 h2 = *(const float4*)(s2 + 4);
                    lo.x += l2.x; lo.y += l2.y; lo.z += l2.z; lo.w += l2.w;
                    hi.x += h2.x; hi.y += h2.y; hi.z += h2.z; hi.w += h2.w;
                }
                int4 pw = { (int)pk2(lo.x, lo.y), (int)pk2(lo.z, lo.w),
                            (int)pk2(hi.x, hi.y), (int)pk2(hi.z, hi.w) };
                *(int4*)((char*)Ash + off) = pw;
            }
            {
                const float* sp = W + (size_t)(bcol + row) * K + k0 + kc;
                float4 lo = *(const float4*)sp;
                float4 hi = *(const float4*)(sp + 4);
                int4 pw = { (int)pk2(lo.x, lo.y), (int)pk2(lo.z, lo.w),
                            (int)pk2(hi.x, hi.y), (int)pk2(hi.z, hi.w) };
                *(int4*)((char*)Wsh + off) = pw;
            }
        }
        __syncthreads();
        #pragma unroll
        for (int ks = 0; ks < BK / 32; ++ks) {
            short8 af[4], bf[4];
            const int kf = ks * 32 + (lane >> 4) * 8;
            #pragma unroll
            for (int mt = 0; mt < 4; ++mt) {
                int row = wm * 64 + mt * 16 + (lane & 15);
                int off = row * (BK * 2) + ((kf * 2) ^ ((row & 7) << 4));
                af[mt] = *(const short8*)((const char*)Ash + off);
            }
            #pragma unroll
            for (int nt = 0; nt < 4; ++nt) {
                int row = wn * 64 + nt * 16 + (lane & 15);
                int off = row * (BK * 2) + ((kf * 2) ^ ((row & 7) << 4));
                bf[nt] = *(const short8*)((const char*)Wsh + off);
            }
            #pragma unroll
            for (int mt = 0; mt < 4; ++mt)
                #pragma unroll
                for (int nt = 0; nt < 4; ++nt)
                    acc[mt][nt] = __builtin_amdgcn_mfma_f32_16x16x32_bf16(
                        af[mt], bf[nt], acc[mt][nt], 0, 0, 0);
        }
        __syncthreads();
    }
    // epilogue: C/D layout col=lane&15, row=(lane>>4)*4+j (verified gfx950 mapping)
    #pragma unroll
    for (int mt = 0; mt < 4; ++mt) {
        #pragma unroll
        for (int nt = 0; nt < 4; ++nt) {
            int col = bcol + wn * 64 + nt * 16 + (lane & 15);
            float bv = bias[col];
            #pragma unroll
            for (int j = 0; j < 4; ++j) {
                int row = brow + wm * 64 + mt * 16 + (lane >> 4) * 4 + j;
                float v = acc[mt][nt][j] + bv;
                if (RELU) v = fmaxf(v, 0.f);
                if (HAS_RES) v += res[(size_t)row * Ncols + col];
                out[(size_t)row * Ncols + col] = v;
            }
        }
    }
}

// ---------------- per-(graph,head) attention, f32, K/V staged in LDS ----------------
__global__ __launch_bounds__(512) void attn_kernel(
    const float* __restrict__ qkv, float* __restrict__ o)
{
    int g = blockIdx.x >> 3;
    int h = blockIdx.x & 7;
    __shared__ float Ksh[SS][DHD];
    __shared__ float Vsh[SS][DHD];
    int t = threadIdx.x;
    const float* rowp = qkv + (size_t)(g * SS + t) * 384;
    {
        const float* kb = rowp + 128 + h * DHD;
        const float* vb = rowp + 256 + h * DHD;
        #pragma unroll
        for (int i = 0; i < 4; ++i) {
            ((float4*)Ksh[t])[i] = ((const float4*)kb)[i];
            ((float4*)Vsh[t])[i] = ((const float4*)vb)[i];
        }
    }
    float q[DHD];
    {
        const float* qb = rowp + h * DHD;
        #pragma unroll
        for (int i = 0; i < 4; ++i) ((float4*)q)[i] = ((const float4*)qb)[i];
    }
    __syncthreads();
    float acc[DHD] = {};
    float l = 0.f;
    for (int j = 0; j < SS; ++j) {
        float s = 0.f;
        #pragma unroll
        for (int d = 0; d < DHD; ++d) s += q[d] * Ksh[j][d];
        float e = __expf(s * 0.25f);   // logits are O(1): max-subtraction unnecessary
        l += e;
        #pragma unroll
        for (int d = 0; d < DHD; ++d) acc[d] += e * Vsh[j][d];
    }
    float inv = 1.f / l;
    float* ob = o + (size_t)(g * SS + t) * DD + h * DHD;
    #pragma unroll
    for (int d = 0; d < DHD; ++d) acc[d] *= inv;
    #pragma unroll
    for (int i = 0; i < 4; ++i) ((float4*)ob)[i] = ((const float4*)acc)[i];
}

// ---------------- per-column sum / sumsq (for BatchNorm, biased var) ----------------
__global__ __launch_bounds__(256) void colstats(
    const float* __restrict__ t, float* __restrict__ sums)
{
    __shared__ float sh[256];
    int tid = threadIdx.x;
    int col = tid & 127;
    int rh  = tid >> 7;
    size_t base = (size_t)blockIdx.x * 128;
    float s = 0.f, s2 = 0.f;
    for (int r = rh; r < 128; r += 2) {
        float v = t[(base + r) * DD + col];
        s += v; s2 += v * v;
    }
    sh[tid] = s;
    __syncthreads();
    if (tid < 128) atomicAdd(&sums[col], sh[tid] + sh[tid + 128]);
    __syncthreads();
    sh[tid] = s2;
    __syncthreads();
    if (tid < 128) atomicAdd(&sums[DD + col], sh[tid] + sh[tid + 128]);
}

// ---------------- h = BN(t_local) + BN(t_attn) ----------------
__global__ __launch_bounds__(256) void combine_kernel(
    const float* __restrict__ tl, const float* __restrict__ ta,
    const float* __restrict__ stl, const float* __restrict__ sta,
    const float* __restrict__ g1, const float* __restrict__ b1,
    const float* __restrict__ g2, const float* __restrict__ b2,
    float* __restrict__ out)
{
    int idx = blockIdx.x * 256 + threadIdx.x;
    int c0 = (idx * 4) & (DD - 1);
    float4 vl = ((const float4*)tl)[idx];
    float4 va = ((const float4*)ta)[idx];
    float r[4];
    const float* pl = (const float*)&vl;
    const float* pa = (const float*)&va;
    #pragma unroll
    for (int k = 0; k < 4; ++k) {
        int c = c0 + k;
        float mu1 = stl[c] * (1.f / NN);
        float v1  = stl[DD + c] * (1.f / NN) - mu1 * mu1;
        float rs1 = rsqrtf(v1 + BN_EPS);
        float mu2 = sta[c] * (1.f / NN);
        float v2  = sta[DD + c] * (1.f / NN) - mu2 * mu2;
        float rs2 = rsqrtf(v2 + BN_EPS);
        r[k] = (pl[k] - mu1) * rs1 * g1[c] + b1[c]
             + (pa[k] - mu2) * rs2 * g2[c] + b2[c];
    }
    ((float4*)out)[idx] = *(float4*)r;
}

// ---------------- out = BN(t2) ----------------
__global__ __launch_bounds__(256) void final_bn(
    const float* __restrict__ t2, const float* __restrict__ st,
    const float* __restrict__ g, const float* __restrict__ b,
    float* __restrict__ out)
{
    int idx = blockIdx.x * 256 + threadIdx.x;
    int c0 = (idx * 4) & (DD - 1);
    float4 v = ((const float4*)t2)[idx];
    const float* pv = (const float*)&v;
    float r[4];
    #pragma unroll
    for (int k = 0; k < 4; ++k) {
        int c = c0 + k;
        float mu = st[c] * (1.f / NN);
        float va = st[DD + c] * (1.f / NN) - mu * mu;
        float rs = rsqrtf(va + BN_EPS);
        r[k] = (pv[k] - mu) * rs * g[c] + b[c];
    }
    ((float4*)out)[idx] = *(float4*)r;
}

extern "C" void kernel_launch(void* const* d_in, const int* in_sizes, int n_in,
                              void* d_out, int out_size, void* d_ws, size_t ws_size,
                              hipStream_t stream) {
    const float* x    = (const float*)d_in[0];
    const int*   ei   = (const int*)d_in[1];
    const float* ea   = (const float*)d_in[2];
    const float* gw1  = (const float*)d_in[3];
    const float* gb1  = (const float*)d_in[4];
    const float* gw2  = (const float*)d_in[5];
    const float* gb2  = (const float*)d_in[6];
    const float* bn1lg= (const float*)d_in[7];
    const float* bn1lb= (const float*)d_in[8];
    const float* aiw  = (const float*)d_in[9];
    const float* aib  = (const float*)d_in[10];
    const float* aow  = (const float*)d_in[11];
    const float* aob  = (const float*)d_in[12];
    const float* bn1ag= (const float*)d_in[13];
    const float* bn1ab= (const float*)d_in[14];
    const float* fw1  = (const float*)d_in[15];
    const float* fb1  = (const float*)d_in[16];
    const float* fw2  = (const float*)d_in[17];
    const float* fb2  = (const float*)d_in[18];
    const float* bn2g = (const float*)d_in[19];
    const float* bn2b = (const float*)d_in[20];
    float* out = (float*)d_out;
    float* ws  = (float*)d_ws;

    // ws layout (floats); reuse dead buffers to keep peak ~67 MB
    float* t_local = ws;                 // 2,097,152
    float* qkv     = ws + 2097152;       // 6,291,456
    float* o_buf   = ws + 8388608;       // 2,097,152
    float* t_attn  = ws + 10485760;      // 2,097,152
    float* agg     = ws + 12582912;      // 2,097,152
    float* h1      = ws + 14680064;      // 2,097,152
    float* stats   = ws + 16777216;      // 768
    float* hbuf = agg;      // reuse: agg dead after gemm1
    float* f1   = qkv;      // reuse: qkv dead after attention
    float* t2   = t_local;  // reuse: t_local dead after combine

    hipMemsetAsync(agg, 0, (size_t)NN * DD * sizeof(float), stream);
    hipMemsetAsync(stats, 0, 768 * sizeof(float), stream);

    // --- local branch
    gine_scatter<<<NE * 32 / 256, 256, 0, stream>>>(x, ei, ei + NE, ea, agg);
    gemm_bt<true, true, false><<<dim3(NN / 128, 1), 256, 0, stream>>>(
        x, agg, gw1, gb1, nullptr, h1, 128, 128);
    gemm_bt<false, false, true><<<dim3(NN / 128, 1), 256, 0, stream>>>(
        h1, nullptr, gw2, gb2, x, t_local, 128, 128);
    colstats<<<NN / 128, 256, 0, stream>>>(t_local, stats);

    // --- global branch
    gemm_bt<false, false, false><<<dim3(NN / 128, 3), 256, 0, stream>>>(
        x, nullptr, aiw, aib, nullptr, qkv, 128, 384);
    attn_kernel<<<NG * NH, 512, 0, stream>>>(qkv, o_buf);
    gemm_bt<false, false, true><<<dim3(NN / 128, 1), 256, 0, stream>>>(
        o_buf, nullptr, aow, aob, x, t_attn, 128, 128);
    colstats<<<NN / 128, 256, 0, stream>>>(t_attn, stats + 256);

    // --- combine + FF
    combine_kernel<<<NN * DD / 4 / 256, 256, 0, stream>>>(
        t_local, t_attn, stats, stats + 256, bn1lg, bn1lb, bn1ag, bn1ab, hbuf);
    gemm_bt<true, false, false><<<dim3(NN / 128, 2), 256, 0, stream>>>(
        hbuf, nullptr, fw1, fb1, nullptr, f1, 128, 256);
    gemm_bt<false, false, true><<<dim3(NN / 128, 1), 256, 0, stream>>>(
        f1, nullptr, fw2, fb2, hbuf, t2, 256, 128);
    colstats<<<NN / 128, 256, 0, stream>>>(t2, stats + 512);
    final_bn<<<NN * DD / 4 / 256, 256, 0, stream>>>(t2, stats + 512, bn2g, bn2b, out);
}

// Round 2
// 532.861 us; speedup vs baseline: 1.6091x; 1.6091x over previous
//
#include <hip/hip_runtime.h>
#include <hip/hip_bf16.h>

typedef __attribute__((ext_vector_type(8))) short short8;
typedef __attribute__((ext_vector_type(4))) float f32x4;

#define NN 16384
#define DD 128
#define NE 262144
#define NG 32
#define SS 512
#define NH 8
#define DHD 16
#define EPG 8192   // edges per graph
#define BN_EPS 1e-5f

__device__ __forceinline__ unsigned int pk2(float a, float b) {
    union { __hip_bfloat16 h; unsigned short u; } ca, cb;
    ca.h = __float2bfloat16(a);
    cb.h = __float2bfloat16(b);
    return (unsigned int)ca.u | ((unsigned int)cb.u << 16);
}

// -------- GINE scatter via per-(graph, feature-chunk) LDS slab; no global atomics ---
// block = (g = id&31, q = id>>5): graph g, feature chunk q (16 floats).
// id = q*32+g keeps all 8 q-chunks of a graph on ONE XCD (ids congruent mod 8)
// so edge_attr 128B lines split across q-pairs are L2 hits on the second read.
__global__ __launch_bounds__(512) void gine_scatter_lds(
    const float* __restrict__ x, const int* __restrict__ src, const int* __restrict__ dst,
    const float* __restrict__ ea, float* __restrict__ agg)
{
    __shared__ float slab[512 * 17];   // stride 17: LDS-atomic banks spread
    const int g = blockIdx.x & 31;
    const int q = blockIdx.x >> 5;
    const int t = threadIdx.x;
    for (int i = t; i < 512 * 17; i += 512) slab[i] = 0.f;
    __syncthreads();

    const int ebase = g * EPG;
    const int lane4 = t & 3;
    const int esub  = t >> 2;           // 128 edges per iteration
    #pragma unroll 4
    for (int it = 0; it < EPG / 128; ++it) {
        int e = ebase + it * 128 + esub;
        int s = src[e];
        int d = dst[e] - g * SS;
        float4 xv = *(const float4*)(x  + (size_t)s * DD + q * 16 + lane4 * 4);
        float4 ev = *(const float4*)(ea + (size_t)e * DD + q * 16 + lane4 * 4);
        float m0 = fmaxf(xv.x + ev.x, 0.f);
        float m1 = fmaxf(xv.y + ev.y, 0.f);
        float m2 = fmaxf(xv.z + ev.z, 0.f);
        float m3 = fmaxf(xv.w + ev.w, 0.f);
        float* p = slab + d * 17 + lane4 * 4;
        atomicAdd(p + 0, m0);
        atomicAdd(p + 1, m1);
        atomicAdd(p + 2, m2);
        atomicAdd(p + 3, m3);
    }
    __syncthreads();
    // writeout: 512 rows x 16 floats, coalesced float4
    for (int i = t; i < 512 * 4; i += 512) {
        int r = i >> 2;
        int c = (i & 3) * 4;
        float4 v = { slab[r * 17 + c], slab[r * 17 + c + 1],
                     slab[r * 17 + c + 2], slab[r * 17 + c + 3] };
        *(float4*)(agg + ((size_t)(g * SS + r)) * DD + q * 16 + c) = v;
    }
}

// ---------------- bf16 MFMA GEMM, BT layout: out = epi(A(+A2) @ W^T + bias) (+res) --
// A: [M,K] f32 row-major, W: [Ncols,K] f32 row-major. BM=BN=128, BK=64, 4 waves (2x2).
// STATS: fuse per-column sum/sumsq (BatchNorm) — requires Ncols==128, gridDim.y==1.
template<bool RELU, bool ADD_A2, bool HAS_RES, bool STATS>
__global__ __launch_bounds__(256) void gemm_bt(
    const float* __restrict__ A, const float* __restrict__ A2,
    const float* __restrict__ W, const float* __restrict__ bias,
    const float* __restrict__ res, float* __restrict__ out,
    float* __restrict__ stats, int K, int Ncols)
{
    constexpr int BK = 64;
    __shared__ unsigned short Ash[128 * BK];
    __shared__ unsigned short Wsh[128 * BK];
    __shared__ float ssh[256];
    const int tid  = threadIdx.x;
    const int lane = tid & 63;
    const int wid  = tid >> 6;
    const int wm   = wid >> 1, wn = wid & 1;
    const int brow = blockIdx.x * 128;
    const int bcol = blockIdx.y * 128;

    f32x4 acc[4][4] = {};

    for (int k0 = 0; k0 < K; k0 += BK) {
        #pragma unroll
        for (int i = 0; i < 4; ++i) {
            int idx = tid + 256 * i;
            int row = idx >> 3;
            int kc  = (idx & 7) * 8;
            int off = row * (BK * 2) + ((kc * 2) ^ ((row & 7) << 4));
            {
                const float* sp = A + (size_t)(brow + row) * K + k0 + kc;
                float4 lo = *(const float4*)sp;
                float4 hi = *(const float4*)(sp + 4);
                if (ADD_A2) {
                    const float* s2 = A2 + (size_t)(brow + row) * K + k0 + kc;
                    float4 l2 = *(const float4*)s2;
                    float4 h2 = *(const float4*)(s2 + 4);
                    lo.x += l2.x; lo.y += l2.y; lo.z += l2.z; lo.w += l2.w;
                    hi.x += h2.x; hi.y += h2.y; hi.z += h2.z; hi.w += h2.w;
                }
                int4 pw = { (int)pk2(lo.x, lo.y), (int)pk2(lo.z, lo.w),
                            (int)pk2(hi.x, hi.y), (int)pk2(hi.z, hi.w) };
                *(int4*)((char*)Ash + off) = pw;
            }
            {
                const float* sp = W + (size_t)(bcol + row) * K + k0 + kc;
                float4 lo = *(const float4*)sp;
                float4 hi = *(const float4*)(sp + 4);
                int4 pw = { (int)pk2(lo.x, lo.y), (int)pk2(lo.z, lo.w),
                            (int)pk2(hi.x, hi.y), (int)pk2(hi.z, hi.w) };
                *(int4*)((char*)Wsh + off) = pw;
            }
        }
        __syncthreads();
        #pragma unroll
        for (int ks = 0; ks < BK / 32; ++ks) {
            short8 af[4], bf[4];
            const int kf = ks * 32 + (lane >> 4) * 8;
            #pragma unroll
            for (int mt = 0; mt < 4; ++mt) {
                int row = wm * 64 + mt * 16 + (lane & 15);
                int off = row * (BK * 2) + ((kf * 2) ^ ((row & 7) << 4));
                af[mt] = *(const short8*)((const char*)Ash + off);
            }
            #pragma unroll
            for (int nt = 0; nt < 4; ++nt) {
                int row = wn * 64 + nt * 16 + (lane & 15);
                int off = row * (BK * 2) + ((kf * 2) ^ ((row & 7) << 4));
                bf[nt] = *(const short8*)((const char*)Wsh + off);
            }
            #pragma unroll
            for (int mt = 0; mt < 4; ++mt)
                #pragma unroll
                for (int nt = 0; nt < 4; ++nt)
                    acc[mt][nt] = __builtin_amdgcn_mfma_f32_16x16x32_bf16(
                        af[mt], bf[nt], acc[mt][nt], 0, 0, 0);
        }
        __syncthreads();
    }

    if (STATS) { ssh[tid] = 0.f; __syncthreads(); }

    float cs[4] = {}, cs2[4] = {};
    // epilogue: C/D layout col=lane&15, row=(lane>>4)*4+j (verified gfx950 mapping)
    #pragma unroll
    for (int mt = 0; mt < 4; ++mt) {
        #pragma unroll
        for (int nt = 0; nt < 4; ++nt) {
            int col = bcol + wn * 64 + nt * 16 + (lane & 15);
            float bv = bias[col];
            #pragma unroll
            for (int j = 0; j < 4; ++j) {
                int row = brow + wm * 64 + mt * 16 + (lane >> 4) * 4 + j;
                float v = acc[mt][nt][j] + bv;
                if (RELU) v = fmaxf(v, 0.f);
                if (HAS_RES) v += res[(size_t)row * Ncols + col];
                out[(size_t)row * Ncols + col] = v;
                if (STATS) { cs[nt] += v; cs2[nt] += v * v; }
            }
        }
    }
    if (STATS) {
        #pragma unroll
        for (int nt = 0; nt < 4; ++nt) {
            float s = cs[nt], s2 = cs2[nt];
            s  += __shfl_xor(s, 16);  s  += __shfl_xor(s, 32);
            s2 += __shfl_xor(s2, 16); s2 += __shfl_xor(s2, 32);
            if ((lane >> 4) == 0) {
                int cl = wn * 64 + nt * 16 + (lane & 15);
                atomicAdd(&ssh[cl], s);
                atomicAdd(&ssh[128 + cl], s2);
            }
        }
        __syncthreads();
        if (tid < 128) {
            atomicAdd(&stats[tid], ssh[tid]);
            atomicAdd(&stats[DD + tid], ssh[128 + tid]);
        }
    }
}

// ---------------- per-(graph,head) attention, f32, K/V staged in LDS ----------------
__global__ __launch_bounds__(512) void attn_kernel(
    const float* __restrict__ qkv, float* __restrict__ o)
{
    int g = blockIdx.x >> 3;
    int h = blockIdx.x & 7;
    __shared__ float Ksh[SS][DHD];
    __shared__ float Vsh[SS][DHD];
    int t = threadIdx.x;
    const float* rowp = qkv + (size_t)(g * SS + t) * 384;
    {
        const float* kb = rowp + 128 + h * DHD;
        const float* vb = rowp + 256 + h * DHD;
        #pragma unroll
        for (int i = 0; i < 4; ++i) {
            ((float4*)Ksh[t])[i] = ((const float4*)kb)[i];
            ((float4*)Vsh[t])[i] = ((const float4*)vb)[i];
        }
    }
    float q[DHD];
    {
        const float* qb = rowp + h * DHD;
        #pragma unroll
        for (int i = 0; i < 4; ++i) ((float4*)q)[i] = ((const float4*)qb)[i];
    }
    __syncthreads();
    float acc[DHD] = {};
    float l = 0.f;
    for (int j = 0; j < SS; ++j) {
        float s = 0.f;
        #pragma unroll
        for (int d = 0; d < DHD; ++d) s += q[d] * Ksh[j][d];
        float e = __expf(s * 0.25f);   // logits are O(1): max-subtraction unnecessary
        l += e;
        #pragma unroll
        for (int d = 0; d < DHD; ++d) acc[d] += e * Vsh[j][d];
    }
    float inv = 1.f / l;
    float* ob = o + (size_t)(g * SS + t) * DD + h * DHD;
    #pragma unroll
    for (int d = 0; d < DHD; ++d) acc[d] *= inv;
    #pragma unroll
    for (int i = 0; i < 4; ++i) ((float4*)ob)[i] = ((const float4*)acc)[i];
}

// ---------------- h = BN(t_local) + BN(t_attn) ----------------
__global__ __launch_bounds__(256) void combine_kernel(
    const float* __restrict__ tl, const float* __restrict__ ta,
    const float* __restrict__ stl, const float* __restrict__ sta,
    const float* __restrict__ g1, const float* __restrict__ b1,
    const float* __restrict__ g2, const float* __restrict__ b2,
    float* __restrict__ out)
{
    int idx = blockIdx.x * 256 + threadIdx.x;
    int c0 = (idx * 4) & (DD - 1);
    float4 vl = ((const float4*)tl)[idx];
    float4 va = ((const float4*)ta)[idx];
    float r[4];
    const float* pl = (const float*)&vl;
    const float* pa = (const float*)&va;
    #pragma unroll
    for (int k = 0; k < 4; ++k) {
        int c = c0 + k;
        float mu1 = stl[c] * (1.f / NN);
        float v1  = stl[DD + c] * (1.f / NN) - mu1 * mu1;
        float rs1 = rsqrtf(v1 + BN_EPS);
        float mu2 = sta[c] * (1.f / NN);
        float v2  = sta[DD + c] * (1.f / NN) - mu2 * mu2;
        float rs2 = rsqrtf(v2 + BN_EPS);
        r[k] = (pl[k] - mu1) * rs1 * g1[c] + b1[c]
             + (pa[k] - mu2) * rs2 * g2[c] + b2[c];
    }
    ((float4*)out)[idx] = *(float4*)r;
}

// ---------------- out = BN(t2) ----------------
__global__ __launch_bounds__(256) void final_bn(
    const float* __restrict__ t2, const float* __restrict__ st,
    const float* __restrict__ g, const float* __restrict__ b,
    float* __restrict__ out)
{
    int idx = blockIdx.x * 256 + threadIdx.x;
    int c0 = (idx * 4) & (DD - 1);
    float4 v = ((const float4*)t2)[idx];
    const float* pv = (const float*)&v;
    float r[4];
    #pragma unroll
    for (int k = 0; k < 4; ++k) {
        int c = c0 + k;
        float mu = st[c] * (1.f / NN);
        float va = st[DD + c] * (1.f / NN) - mu * mu;
        float rs = rsqrtf(va + BN_EPS);
        r[k] = (pv[k] - mu) * rs * g[c] + b[c];
    }
    ((float4*)out)[idx] = *(float4*)r;
}

extern "C" void kernel_launch(void* const* d_in, const int* in_sizes, int n_in,
                              void* d_out, int out_size, void* d_ws, size_t ws_size,
                              hipStream_t stream) {
    const float* x    = (const float*)d_in[0];
    const int*   ei   = (const int*)d_in[1];
    const float* ea   = (const float*)d_in[2];
    const float* gw1  = (const float*)d_in[3];
    const float* gb1  = (const float*)d_in[4];
    const float* gw2  = (const float*)d_in[5];
    const float* gb2  = (const float*)d_in[6];
    const float* bn1lg= (const float*)d_in[7];
    const float* bn1lb= (const float*)d_in[8];
    const float* aiw  = (const float*)d_in[9];
    const float* aib  = (const float*)d_in[10];
    const float* aow  = (const float*)d_in[11];
    const float* aob  = (const float*)d_in[12];
    const float* bn1ag= (const float*)d_in[13];
    const float* bn1ab= (const float*)d_in[14];
    const float* fw1  = (const float*)d_in[15];
    const float* fb1  = (const float*)d_in[16];
    const float* fw2  = (const float*)d_in[17];
    const float* fb2  = (const float*)d_in[18];
    const float* bn2g = (const float*)d_in[19];
    const float* bn2b = (const float*)d_in[20];
    float* out = (float*)d_out;
    float* ws  = (float*)d_ws;

    float* t_local = ws;                 // 2,097,152
    float* qkv     = ws + 2097152;       // 6,291,456
    float* o_buf   = ws + 8388608;       // 2,097,152
    float* t_attn  = ws + 10485760;      // 2,097,152
    float* agg     = ws + 12582912;      // 2,097,152
    float* h1      = ws + 14680064;      // 2,097,152
    float* stats   = ws + 16777216;      // 768
    float* hbuf = agg;      // reuse: agg dead after gemm1
    float* f1   = qkv;      // reuse: qkv dead after attention
    float* t2   = t_local;  // reuse: t_local dead after combine

    hipMemsetAsync(stats, 0, 768 * sizeof(float), stream);

    // --- local branch (agg fully overwritten by scatter; no memset needed)
    gine_scatter_lds<<<256, 512, 0, stream>>>(x, ei, ei + NE, ea, agg);
    gemm_bt<true, true, false, false><<<dim3(NN / 128, 1), 256, 0, stream>>>(
        x, agg, gw1, gb1, nullptr, h1, nullptr, 128, 128);
    gemm_bt<false, false, true, true><<<dim3(NN / 128, 1), 256, 0, stream>>>(
        h1, nullptr, gw2, gb2, x, t_local, stats, 128, 128);

    // --- global branch
    gemm_bt<false, false, false, false><<<dim3(NN / 128, 3), 256, 0, stream>>>(
        x, nullptr, aiw, aib, nullptr, qkv, nullptr, 128, 384);
    attn_kernel<<<NG * NH, 512, 0, stream>>>(qkv, o_buf);
    gemm_bt<false, false, true, true><<<dim3(NN / 128, 1), 256, 0, stream>>>(
        o_buf, nullptr, aow, aob, x, t_attn, stats + 256, 128, 128);

    // --- combine + FF
    combine_kernel<<<NN * DD / 4 / 256, 256, 0, stream>>>(
        t_local, t_attn, stats, stats + 256, bn1lg, bn1lb, bn1ag, bn1ab, hbuf);
    gemm_bt<true, false, false, false><<<dim3(NN / 128, 2), 256, 0, stream>>>(
        hbuf, nullptr, fw1, fb1, nullptr, f1, nullptr, 128, 256);
    gemm_bt<false, false, true, true><<<dim3(NN / 128, 1), 256, 0, stream>>>(
        f1, nullptr, fw2, fb2, hbuf, t2, stats + 512, 256, 128);
    final_bn<<<NN * DD / 4 / 256, 256, 0, stream>>>(t2, stats + 512, bn2g, bn2b, out);
}